// Round 5
// baseline (1365.748 us; speedup 1.0000x reference)
//
#include <hip/hip_runtime.h>
#include <math.h>

#define T_LEN 1016
#define XSTRIDE 65024   // 64*1016

typedef __attribute__((ext_vector_type(8))) short bf16x8;
typedef __attribute__((ext_vector_type(4))) float f32x4;
typedef __attribute__((ext_vector_type(4))) unsigned int uint4v;
typedef __attribute__((ext_vector_type(2))) unsigned int uint2v;

static __device__ __forceinline__ unsigned pk_bf16(float lo, float hi) {
    unsigned r;
    asm("v_cvt_pk_bf16_f32 %0, %1, %2" : "=v"(r) : "v"(lo), "v"(hi));
    return r;
}

#define F4C(v, i) ((i) == 0 ? (v).x : (i) == 1 ? (v).y : (i) == 2 ? (v).z : (v).w)

// ---------------- Kernel A: mu-law encode + q output + embedding ----------------
__global__ void k_mulaw_embed(const float* __restrict__ audio,
                              const float* __restrict__ embed,
                              float* __restrict__ x0,
                              float* __restrict__ q_out)
{
    int t = blockIdx.x * blockDim.x + threadIdx.x;
    if (t >= T_LEN) return;
    float x = audio[t];
    x = fminf(1.f, fmaxf(-1.f, x));
    float ax = fabsf(x);
    float sg = (x > 0.f) ? 1.f : ((x < 0.f) ? -1.f : 0.f);
    float m = sg * log1pf(255.f * ax) / log1pf(255.f);
    float v = (m + 1.f) * 0.5f * 255.f + 0.5f;
    v = fminf(255.f, fmaxf(0.f, v));
    int q = (int)v;
    q_out[t] = (float)q;
    const float* e = embed + q * 64;
    for (int c = 0; c < 64; ++c) x0[(size_t)c * T_LEN + t] = e[c];
}

// ---------------- fp32 -> bf16 convert (w_cond) ----------------
__global__ __launch_bounds__(256) void k_cvt_bf16(const float* __restrict__ src,
                                                  unsigned short* __restrict__ dst)
{
    int i4 = (blockIdx.x * 256 + threadIdx.x) * 4;
    float4 v = *(const float4*)&src[i4];
    uint2v p;
    p.x = pk_bf16(v.x, v.y);
    p.y = pk_bf16(v.z, v.w);
    *(uint2v*)&dst[i4] = p;
}

// ---------------- build F2T[oct][2c+tap] bf16 (coalesced, LDS transpose) ----------------
// F2T[oct][2c] = f[c][oct], F2T[oct][2c+1] = f[c][oct+1]; row 127 zero.
// grid 64 blocks x 32 c-rows.
__global__ __launch_bounds__(256) void k_build_f2t(const float* __restrict__ F,
                                                   unsigned short* __restrict__ f2t)
{
    __shared__ float fs[32][129];
    const int tid = threadIdx.x;
    const int c0 = blockIdx.x * 32;
    #pragma unroll
    for (int p = 0; p < 4; ++p) {
        int idx = p * 256 + tid;          // 0..1023
        int cl = idx >> 5;                // 0..31
        int o4 = (idx & 31) * 4;
        float4 v = *(const float4*)&F[(size_t)(c0 + cl) * 128 + o4];
        fs[cl][o4 + 0] = v.x; fs[cl][o4 + 1] = v.y;
        fs[cl][o4 + 2] = v.z; fs[cl][o4 + 3] = v.w;
    }
    __syncthreads();
    for (int idx = tid; idx < 127 * 32; idx += 256) {
        int oct = idx >> 5, cc = idx & 31;
        *(unsigned*)&f2t[(size_t)oct * 4096 + 2 * (c0 + cc)] = pk_bf16(fs[cc][oct], fs[cc][oct + 1]);
    }
    if (tid < 32)
        *(unsigned*)&f2t[(size_t)127 * 4096 + 2 * (c0 + tid)] = 0u;
}

// ---------------- MFMA upsample (verified round 4) ----------------
__global__ __launch_bounds__(256) void k_upsample_mfma(
    const unsigned short* __restrict__ f2t,  // [128][4096] bf16
    const float* __restrict__ W,             // [2048][2048][16] f32
    const float* __restrict__ b_up,          // [2048]
    unsigned short* __restrict__ cond0)      // [2048][1024] bf16
{
    __shared__ char lds_raw[49152];

    const int tid  = threadIdx.x;
    const int wave = tid >> 6;
    const int lane = tid & 63;
    const int ob   = blockIdx.x * 8;
    const int wm = wave & 1, wn = wave >> 1;
    const int row = lane & 15, g = lane >> 4;

    int wbyte[2][4];
    size_t aWoff[2];
    #pragma unroll
    for (int j = 0; j < 2; ++j) {
        int flat = j * 256 + tid;
        int cp = flat >> 4;
        int op = (flat >> 1) & 7;
        int h  = flat & 1;
        aWoff[j] = (size_t)cp * 32768 + (size_t)(ob + op) * 16 + h * 4;
        #pragma unroll
        for (int i = 0; i < 4; ++i) {
            int ph = h * 4 + i;
            int m  = op * 8 + ph;
            wbyte[j][i] = m * 128 + ((cp * 4) ^ (ph << 4));
        }
    }
    const int bn = tid >> 1, bhalf = tid & 1;
    int bSrc[4], bbw[4];
    #pragma unroll
    for (int q = 0; q < 4; ++q) {
        bSrc[q] = bn * 4096 + bhalf * 32 + q * 8;
        bbw[q]  = bn * 128 + ((((bhalf * 4 + q) * 16)) ^ ((bn & 7) << 4));
    }
    int abyte[2][2], bbyte[2][4];
    #pragma unroll
    for (int s = 0; s < 2; ++s) {
        #pragma unroll
        for (int fm = 0; fm < 2; ++fm) {
            int m = wm * 32 + fm * 16 + row;
            abyte[s][fm] = m * 128 + (((s * 4 + g) * 16) ^ ((m & 7) << 4));
        }
        #pragma unroll
        for (int fn = 0; fn < 4; ++fn) {
            int n = wn * 64 + fn * 16 + row;
            bbyte[s][fn] = n * 128 + (((s * 4 + g) * 16) ^ ((n & 7) << 4));
        }
    }

    f32x4 acc[2][4];
    #pragma unroll
    for (int a = 0; a < 2; ++a)
        #pragma unroll
        for (int b = 0; b < 4; ++b) acc[a][b] = (f32x4){0.f, 0.f, 0.f, 0.f};

    float4 aL[2], aH[2];
    uint4v bstg[4];

    #pragma unroll
    for (int j = 0; j < 2; ++j) {
        const float* p = W + aWoff[j];
        aL[j] = *(const float4*)p;
        aH[j] = *(const float4*)(p + 8);
    }
    #pragma unroll
    for (int q = 0; q < 4; ++q)
        bstg[q] = *(const uint4v*)(f2t + bSrc[q]);
    #pragma unroll
    for (int j = 0; j < 2; ++j)
        #pragma unroll
        for (int i = 0; i < 4; ++i)
            *(unsigned*)(lds_raw + wbyte[j][i]) = pk_bf16(F4C(aH[j], i), F4C(aL[j], i));
    #pragma unroll
    for (int q = 0; q < 4; ++q)
        *(uint4v*)(lds_raw + 16384 + bbw[q]) = bstg[q];
    __syncthreads();

    int cur = 0;
    for (int r = 0; r < 64; ++r) {
        const bool more = (r < 63);
        if (more) {
            const size_t roff = (size_t)(r + 1) * (32 * 32768);
            #pragma unroll
            for (int j = 0; j < 2; ++j) {
                const float* p = W + aWoff[j] + roff;
                aL[j] = *(const float4*)p;
                aH[j] = *(const float4*)(p + 8);
            }
            const int bo = (r + 1) * 64;
            #pragma unroll
            for (int q = 0; q < 4; ++q)
                bstg[q] = *(const uint4v*)(f2t + bSrc[q] + bo);
        }
        {
            const char* As = lds_raw + cur * 8192;
            const char* Bs = lds_raw + 16384 + cur * 16384;
            #pragma unroll
            for (int s = 0; s < 2; ++s) {
                bf16x8 af[2];
                #pragma unroll
                for (int fm = 0; fm < 2; ++fm)
                    af[fm] = *(const bf16x8*)(As + abyte[s][fm]);
                #pragma unroll
                for (int fn = 0; fn < 4; ++fn) {
                    bf16x8 bf = *(const bf16x8*)(Bs + bbyte[s][fn]);
                    acc[0][fn] = __builtin_amdgcn_mfma_f32_16x16x32_bf16(af[0], bf, acc[0][fn], 0, 0, 0);
                    acc[1][fn] = __builtin_amdgcn_mfma_f32_16x16x32_bf16(af[1], bf, acc[1][fn], 0, 0, 0);
                }
            }
        }
        if (more) {
            char* As = lds_raw + (cur ^ 1) * 8192;
            char* Bs = lds_raw + 16384 + (cur ^ 1) * 16384;
            #pragma unroll
            for (int j = 0; j < 2; ++j)
                #pragma unroll
                for (int i = 0; i < 4; ++i)
                    *(unsigned*)(As + wbyte[j][i]) = pk_bf16(F4C(aH[j], i), F4C(aL[j], i));
            #pragma unroll
            for (int q = 0; q < 4; ++q)
                *(uint4v*)(Bs + bbw[q]) = bstg[q];
        }
        __syncthreads();
        cur ^= 1;
    }

    #pragma unroll
    for (int fm = 0; fm < 2; ++fm) {
        const int och = ob + wm * 4 + fm * 2 + (g >> 1);
        const int ph0 = (g & 1) * 4;
        const float bb = b_up[och];
        #pragma unroll
        for (int fn = 0; fn < 4; ++fn) {
            const int oct = wn * 64 + fn * 16 + row;
            if (oct == 127) continue;
            float v0 = acc[fm][fn].x + bb;
            float v1 = acc[fm][fn].y + bb;
            float v2 = acc[fm][fn].z + bb;
            float v3 = acc[fm][fn].w + bb;
            uint2v pkd;
            pkd.x = pk_bf16(v0, v1);
            pkd.y = pk_bf16(v2, v3);
            *(uint2v*)&cond0[(size_t)och * 1024 + oct * 8 + ph0] = pkd;
        }
    }
}

// ---------------- bf16 transpose (verified round 4) ----------------
__global__ __launch_bounds__(256) void k_transpose_bf16(const unsigned short* __restrict__ src,
                                                        unsigned short* __restrict__ dst)
{
    __shared__ unsigned short sm[64][68];
    const int t0 = blockIdx.x * 64, o0 = blockIdx.y * 64;
    const int tid = threadIdx.x;
    const int r = tid >> 4;
    const int c4 = (tid & 15) * 4;
    #pragma unroll
    for (int p = 0; p < 4; ++p) {
        int o = p * 16 + r;
        ushort4 v = *(const ushort4*)(src + (size_t)(o0 + o) * 1024 + t0 + c4);
        sm[o][c4 + 0] = v.x; sm[o][c4 + 1] = v.y;
        sm[o][c4 + 2] = v.z; sm[o][c4 + 3] = v.w;
    }
    __syncthreads();
    #pragma unroll
    for (int p = 0; p < 4; ++p) {
        int t = p * 16 + r;
        int tg = t0 + t;
        ushort4 v;
        if (tg < 1016) {
            v.x = sm[c4 + 0][t]; v.y = sm[c4 + 1][t];
            v.z = sm[c4 + 2][t]; v.w = sm[c4 + 3][t];
        } else {
            v.x = 0; v.y = 0; v.z = 0; v.w = 0;
        }
        *(ushort4*)(dst + (size_t)tg * 2048 + o0 + c4) = v;
    }
}

// ---------------- MFMA GEMM, direct-global fragments (verified round 4) ----------------
template<int MODE>
__global__ __launch_bounds__(256) void gemm_mfma(
    const unsigned short* __restrict__ A, const unsigned short* __restrict__ Bm,
    const float* __restrict__ bias, void* __restrict__ outp,
    int ldA, int ldB, int K)
{
    const int w = threadIdx.x >> 6, lane = threadIdx.x & 63;
    const int m0 = blockIdx.y * 128 + (w >> 1) * 64;
    const int n0 = blockIdx.x * 128 + (w & 1) * 64;
    const int row = lane & 15, g = lane >> 4;

    f32x4 acc[4][4];
    #pragma unroll
    for (int i = 0; i < 4; ++i)
        #pragma unroll
        for (int j = 0; j < 4; ++j) acc[i][j] = (f32x4){0.f, 0.f, 0.f, 0.f};

    const unsigned short* Ap = A + (size_t)(m0 + row) * ldA + g * 8;
    const unsigned short* Bp = Bm + (size_t)(n0 + row) * ldB + g * 8;

    for (int kk = 0; kk < K; kk += 32) {
        bf16x8 af[4], bf[4];
        #pragma unroll
        for (int fm = 0; fm < 4; ++fm)
            af[fm] = *(const bf16x8*)(Ap + (size_t)fm * 16 * ldA + kk);
        #pragma unroll
        for (int fn = 0; fn < 4; ++fn)
            bf[fn] = *(const bf16x8*)(Bp + (size_t)fn * 16 * ldB + kk);
        #pragma unroll
        for (int fm = 0; fm < 4; ++fm)
            #pragma unroll
            for (int fn = 0; fn < 4; ++fn)
                acc[fm][fn] = __builtin_amdgcn_mfma_f32_16x16x32_bf16(af[fm], bf[fn], acc[fm][fn], 0, 0, 0);
    }

    #pragma unroll
    for (int fm = 0; fm < 4; ++fm) {
        #pragma unroll
        for (int fn = 0; fn < 4; ++fn) {
            const int n_g = n0 + fn * 16 + row;
            const int m_b = m0 + fm * 16 + g * 4;
            if (MODE == 0) {
                unsigned short* o = (unsigned short*)outp;
                const float bb = bias[n_g];
                #pragma unroll
                for (int r = 0; r < 4; ++r) {
                    float v = F4C(acc[fm][fn], r) + bb;
                    o[(size_t)(m_b + r) * 2048 + n_g] = (unsigned short)pk_bf16(v, v);
                }
            } else {
                float* o = (float*)outp;
                if (n_g < 1016) {
                    #pragma unroll
                    for (int r = 0; r < 4; ++r) {
                        float v = F4C(acc[fm][fn], r) + bias[m_b + r];
                        o[(size_t)(m_b + r) * 1016 + n_g] = v;
                    }
                }
            }
        }
    }
}

// ---------------- Fused 16-layer chain + output head ----------------
// 127 blocks, block b owns t in [8b, 8b+8). Flag-synced causal pipeline:
// layer i reads buf[i] (buf[0]=x0, buf[i>=1]=xch[(i-1)]), writes buf[i+1].
// Own x window + skip accumulator stay resident; head fused (block-local in t).
__global__ __launch_bounds__(256) void k_chain(
    const float* __restrict__ x0,
    float* __restrict__ xch,             // 15 * XSTRIDE used
    const float* __restrict__ cond_acts, // [16][128][1016]
    const float* __restrict__ w_dil, const float* __restrict__ b_dil,
    const float* __restrict__ w_res, const float* __restrict__ b_res,
    const float* __restrict__ w_skip, const float* __restrict__ b_skip,
    const float* __restrict__ w_out, const float* __restrict__ w_end,
    float* __restrict__ out,
    int* __restrict__ prog)              // 127 flags, stride 16 ints
{
    // layouts: xsA/xow = [c][parity][4] (parity = t&1, j = t>>1) -> float4 per (c,parity)
    __shared__ float xsA[64 * 8];
    __shared__ float xow[64 * 8];
    __shared__ float ia_s[128 * 9];
    __shared__ float acts_s[64 * 8];     // [c][t]
    __shared__ float h1_s[256 * 8];      // [o][t]
    __shared__ float h2_s[256 * 8];

    const int tid = threadIdx.x;
    const int b = blockIdx.x;
    const int t0 = b * 8;

    // stage own window
    #pragma unroll
    for (int r = 0; r < 2; ++r) {
        int idx = tid + r * 256;
        int c = idx >> 3, t = idx & 7;
        xow[c * 8 + (t & 1) * 4 + (t >> 1)] = x0[c * T_LEN + t0 + t];
    }
    float skip_r[8] = {0.f, 0.f, 0.f, 0.f, 0.f, 0.f, 0.f, 0.f};

    for (int i = 0; i < 16; ++i) {
        const int d = 1 << (i & 7);
        const float* xin = (i == 0) ? x0 : (xch + (size_t)(i - 1) * XSTRIDE);

        if (i > 0) {
            int K = (d + 7) >> 3;
            int nb = (K < b) ? K : b;
            if (tid < nb) {
                const int* fl = prog + (b - 1 - tid) * 16;
                while (__hip_atomic_load(fl, __ATOMIC_RELAXED, __HIP_MEMORY_SCOPE_AGENT) < i)
                    __builtin_amdgcn_s_sleep(2);
            }
            __syncthreads();
            __threadfence();    // acquire: fresh view of xin
        }
        // stage A-window (x[t0-d+t])
        #pragma unroll
        for (int r = 0; r < 2; ++r) {
            int idx = tid + r * 256;
            int c = idx >> 3, t = idx & 7;
            int tg = t0 - d + t;
            xsA[c * 8 + (t & 1) * 4 + (t >> 1)] = (tg >= 0) ? xin[c * T_LEN + tg] : 0.f;
        }
        __syncthreads();

        // ---- ia: o in [0,128), tq parity, t = tq + 2*s ----
        {
            const int o = tid & 127, tq = tid >> 7;
            const float* cd = cond_acts + ((size_t)i * 128 + o) * T_LEN + t0;
            float ia[4];
            #pragma unroll
            for (int s2 = 0; s2 < 4; ++s2) ia[s2] = b_dil[i * 128 + o] + cd[tq + 2 * s2];
            const float* wd = w_dil + (size_t)i * 16384 + o * 128;
            for (int c = 0; c < 64; ++c) {
                float2 wv = *(const float2*)&wd[2 * c];
                float4 xa = *(const float4*)&xsA[c * 8 + tq * 4];
                float4 xo = *(const float4*)&xow[c * 8 + tq * 4];
                ia[0] += wv.x * xa.x + wv.y * xo.x;
                ia[1] += wv.x * xa.y + wv.y * xo.y;
                ia[2] += wv.x * xa.z + wv.y * xo.z;
                ia[3] += wv.x * xa.w + wv.y * xo.w;
            }
            #pragma unroll
            for (int s2 = 0; s2 < 4; ++s2) ia_s[o * 9 + tq + 2 * s2] = ia[s2];
        }
        __syncthreads();

        // ---- gate ----
        #pragma unroll
        for (int rep = 0; rep < 2; ++rep) {
            int idx = tid + rep * 256;
            int c = idx >> 3, t = idx & 7;
            float a = ia_s[c * 9 + t];
            float gg = ia_s[(c + 64) * 9 + t];
            acts_s[c * 8 + t] = tanhf(a) * (1.f / (1.f + expf(-gg)));
        }
        __syncthreads();

        // ---- skip accumulate (o = tid) ----
        {
            const float* wk = w_skip + (size_t)i * 16384 + tid * 64;
            float acc[8] = {0.f, 0.f, 0.f, 0.f, 0.f, 0.f, 0.f, 0.f};
            for (int c4 = 0; c4 < 16; ++c4) {
                float4 wv = *(const float4*)&wk[c4 * 4];
                #pragma unroll
                for (int u = 0; u < 4; ++u) {
                    float w1 = F4C(wv, u);
                    float4 a0 = *(const float4*)&acts_s[(c4 * 4 + u) * 8];
                    float4 a1 = *(const float4*)&acts_s[(c4 * 4 + u) * 8 + 4];
                    acc[0] += w1 * a0.x; acc[1] += w1 * a0.y;
                    acc[2] += w1 * a0.z; acc[3] += w1 * a0.w;
                    acc[4] += w1 * a1.x; acc[5] += w1 * a1.y;
                    acc[6] += w1 * a1.z; acc[7] += w1 * a1.w;
                }
            }
            float bb = b_skip[i * 256 + tid];
            #pragma unroll
            for (int t = 0; t < 8; ++t) skip_r[t] += acc[t] + bb;
        }

        // ---- res + x update + publish ----
        if (i < 15) {
            float* xo_g = xch + (size_t)i * XSTRIDE;
            #pragma unroll
            for (int rep = 0; rep < 2; ++rep) {
                int idx = tid + rep * 256;
                int c = idx >> 3, t = idx & 7;
                float r = b_res[i * 64 + c];
                const float* wr = w_res + (size_t)i * 4096 + c * 64;
                for (int cc = 0; cc < 64; ++cc) r += wr[cc] * acts_s[cc * 8 + t];
                int xoff = c * 8 + (t & 1) * 4 + (t >> 1);
                r += xow[xoff];
                xow[xoff] = r;
                xo_g[c * T_LEN + t0 + t] = r;
            }
            __syncthreads();
            __threadfence();
            if (tid == 0)
                __hip_atomic_store(prog + b * 16, i + 1, __ATOMIC_RELEASE, __HIP_MEMORY_SCOPE_AGENT);
        } else {
            __syncthreads();
        }
    }

    // ---- head: h1 = relu(skip); h2 = relu(w_out@h1); y = w_end@h2, shifted ----
    {
        float4 lo, hi;
        lo.x = fmaxf(skip_r[0], 0.f); lo.y = fmaxf(skip_r[1], 0.f);
        lo.z = fmaxf(skip_r[2], 0.f); lo.w = fmaxf(skip_r[3], 0.f);
        hi.x = fmaxf(skip_r[4], 0.f); hi.y = fmaxf(skip_r[5], 0.f);
        hi.z = fmaxf(skip_r[6], 0.f); hi.w = fmaxf(skip_r[7], 0.f);
        *(float4*)&h1_s[tid * 8] = lo;
        *(float4*)&h1_s[tid * 8 + 4] = hi;
    }
    __syncthreads();
    {
        const float* wo = w_out + tid * 256;
        float acc[8] = {0.f, 0.f, 0.f, 0.f, 0.f, 0.f, 0.f, 0.f};
        for (int o4 = 0; o4 < 64; ++o4) {
            float4 wv = *(const float4*)&wo[o4 * 4];
            #pragma unroll
            for (int u = 0; u < 4; ++u) {
                float w1 = F4C(wv, u);
                float4 a0 = *(const float4*)&h1_s[(o4 * 4 + u) * 8];
                float4 a1 = *(const float4*)&h1_s[(o4 * 4 + u) * 8 + 4];
                acc[0] += w1 * a0.x; acc[1] += w1 * a0.y;
                acc[2] += w1 * a0.z; acc[3] += w1 * a0.w;
                acc[4] += w1 * a1.x; acc[5] += w1 * a1.y;
                acc[6] += w1 * a1.z; acc[7] += w1 * a1.w;
            }
        }
        float4 lo, hi;
        lo.x = fmaxf(acc[0], 0.f); lo.y = fmaxf(acc[1], 0.f);
        lo.z = fmaxf(acc[2], 0.f); lo.w = fmaxf(acc[3], 0.f);
        hi.x = fmaxf(acc[4], 0.f); hi.y = fmaxf(acc[5], 0.f);
        hi.z = fmaxf(acc[6], 0.f); hi.w = fmaxf(acc[7], 0.f);
        *(float4*)&h2_s[tid * 8] = lo;
        *(float4*)&h2_s[tid * 8 + 4] = hi;
    }
    __syncthreads();
    {
        const float* we = w_end + tid * 256;
        float acc[8] = {0.f, 0.f, 0.f, 0.f, 0.f, 0.f, 0.f, 0.f};
        for (int m4 = 0; m4 < 64; ++m4) {
            float4 wv = *(const float4*)&we[m4 * 4];
            #pragma unroll
            for (int u = 0; u < 4; ++u) {
                float w1 = F4C(wv, u);
                float4 a0 = *(const float4*)&h2_s[(m4 * 4 + u) * 8];
                float4 a1 = *(const float4*)&h2_s[(m4 * 4 + u) * 8 + 4];
                acc[0] += w1 * a0.x; acc[1] += w1 * a0.y;
                acc[2] += w1 * a0.z; acc[3] += w1 * a0.w;
                acc[4] += w1 * a1.x; acc[5] += w1 * a1.y;
                acc[6] += w1 * a1.z; acc[7] += w1 * a1.w;
            }
        }
        #pragma unroll
        for (int t = 0; t < 8; ++t) {
            int tg = t0 + 1 + t;
            if (tg < T_LEN) out[tid * T_LEN + tg] = acc[t];
        }
        if (b == 0) out[tid * T_LEN] = 0.f;
    }
}

// ---------------- host launch ----------------
extern "C" void kernel_launch(void* const* d_in, const int* in_sizes, int n_in,
                              void* d_out, int out_size, void* d_ws, size_t ws_size,
                              hipStream_t stream)
{
    const float* features = (const float*)d_in[0];
    const float* audio    = (const float*)d_in[1];
    const float* w_up     = (const float*)d_in[2];
    const float* b_up     = (const float*)d_in[3];
    const float* w_cond   = (const float*)d_in[4];
    const float* b_cond   = (const float*)d_in[5];
    const float* embed    = (const float*)d_in[6];
    const float* w_dil    = (const float*)d_in[7];
    const float* b_dil    = (const float*)d_in[8];
    const float* w_res    = (const float*)d_in[9];
    const float* b_res    = (const float*)d_in[10];
    const float* w_skip   = (const float*)d_in[11];
    const float* b_skip   = (const float*)d_in[12];
    const float* w_out    = (const float*)d_in[13];
    const float* w_end    = (const float*)d_in[14];
    float* out = (float*)d_out;

    char* base = (char*)d_ws;
    unsigned short* w_cond_b  = (unsigned short*)(base);              // 8 MB
    unsigned short* f2t       = (unsigned short*)(base + 8388608);    // 1 MB
    unsigned short* cond0     = (unsigned short*)(base + 9437184);    // 4 MB
    unsigned short* cond0T    = (unsigned short*)(base + 13631488);   // 4 MB
    unsigned short* condBT    = (unsigned short*)(base + 17825792);   // 4 MB
    float*          cond_acts = (float*)(base + 22020096);            // 8.32 MB
    float*          x0        = (float*)(base + 30343168);            // 260 KB
    float*          xch       = (float*)(base + 30603264);            // 15*260 KB
    int*            prog      = (int*)(base + 34764800);              // 8 KB

    // 0. zero pipeline flags
    hipMemsetAsync(prog, 0, 8192, stream);
    // 1. mu-law + q + embedding
    k_mulaw_embed<<<4, 256, 0, stream>>>(audio, embed, x0, out + 260096);
    // 2. prep: w_cond -> bf16; features -> interleaved F2T
    k_cvt_bf16<<<4096, 256, 0, stream>>>(w_cond, w_cond_b);
    k_build_f2t<<<64, 256, 0, stream>>>(features, f2t);
    // 3. MFMA upsample -> cond0 bf16 [2048][1024]
    k_upsample_mfma<<<256, 256, 0, stream>>>(f2t, w_up, b_up, cond0);
    // 4. transpose -> cond0T [1024][2048]
    k_transpose_bf16<<<dim3(16, 32), 256, 0, stream>>>(cond0, cond0T);
    // 5. G1 (T-form): condBT[t][oc] = cond0T . w_cond^T + b_cond
    gemm_mfma<0><<<dim3(16, 8), 256, 0, stream>>>(cond0T, w_cond_b, b_cond, condBT, 2048, 2048, 2048);
    // 6. G2 (N-form): cond_acts[oc][t] = w_cond . condB + b_cond
    gemm_mfma<1><<<dim3(8, 16), 256, 0, stream>>>(w_cond_b, condBT, b_cond, cond_acts, 2048, 2048, 2048);
    // 7. fused 16-layer chain + head
    k_chain<<<127, 256, 0, stream>>>(x0, xch, cond_acts,
                                     w_dil, b_dil, w_res, b_res, w_skip, b_skip,
                                     w_out, w_end, out, prog);
}